// Round 2
// baseline (437.161 us; speedup 1.0000x reference)
//
#include <hip/hip_runtime.h>
#include <hip/hip_bf16.h>

#define DEV __device__ __forceinline__

// Problem constants
constexpr int BB = 4, NQ1 = 1024, DM = 256, NHH = 8, KK = 49;
constexpr int HWP = 4096;          // 64*64
constexpr int NQT = BB * NQ1;      // 4096 queries

DEV float bflo(unsigned u) { return __uint_as_float(u << 16); }
DEV float bfhi(unsigned u) { return __uint_as_float(u & 0xffff0000u); }

// ---------------- transpose memory (B,C,H,W) -> memT (B,HW,C) bf16 ----------------
__global__ __launch_bounds__(256) void k_transpose(const float* __restrict__ src,
                                                   __hip_bfloat16* __restrict__ dst) {
    __shared__ float tile[32][33];
    int b = blockIdx.z;
    int c0 = blockIdx.y * 32;
    int p0 = blockIdx.x * 32;
    int tx = threadIdx.x, ty = threadIdx.y;
    const float* s = src + ((size_t)b * DM + c0) * HWP + p0;
#pragma unroll
    for (int i = 0; i < 32; i += 8) tile[ty + i][tx] = s[(size_t)(ty + i) * HWP + tx];
    __syncthreads();
    __hip_bfloat16* d = dst + ((size_t)b * HWP + p0) * DM + c0;
#pragma unroll
    for (int i = 0; i < 32; i += 8)
        d[(size_t)(ty + i) * DM + tx] = __float2bfloat16(tile[tx][ty + i]);
}

// ---------------- generic fp32 tiled GEMM (128x64 tile, 8x4 acc) ----------------
// C[m][n] = act( sum_k A[m][k]*B[k][n] + bias[n] )
// bt==1: B stored N x K (access B[n][k])
// act: 0 none, 1 relu, 2 tanh(x)*(*sclp)
// Requires: M % 128 == 0, K % 16 == 0, A rows 16B-aligned at each k0 step.
__global__ __launch_bounds__(256) void gemm_f32(
    const float* __restrict__ A, const float* __restrict__ Bm,
    const float* __restrict__ bias, float* __restrict__ C,
    int M, int N, int K, int lda, int ldb, int ldc,
    long Ab, long Bb, long Cb, long biasb,
    const float* __restrict__ sclp, int act, int bt) {
    int z = blockIdx.z;
    A += (long)z * Ab;
    Bm += (long)z * Bb;
    C += (long)z * Cb;
    if (bias) bias += (long)z * biasb;

    __shared__ float As[16][132];
    __shared__ float Bs[16][68];
    int t = threadIdx.x;
    int tx = t & 15, ty = t >> 4;
    int m0 = blockIdx.y * 128, n0 = blockIdx.x * 64;
    float acc[8][4] = {};

    for (int k0 = 0; k0 < K; k0 += 16) {
        // A tile 128x16
        {
            int m = t >> 1;
            int kq = (t & 1) * 8;
            const float* ap = &A[(size_t)(m0 + m) * lda + k0 + kq];
            float4 a4 = *(const float4*)ap;
            float4 a4b = *(const float4*)(ap + 4);
            As[kq + 0][m] = a4.x;
            As[kq + 1][m] = a4.y;
            As[kq + 2][m] = a4.z;
            As[kq + 3][m] = a4.w;
            As[kq + 4][m] = a4b.x;
            As[kq + 5][m] = a4b.y;
            As[kq + 6][m] = a4b.z;
            As[kq + 7][m] = a4b.w;
        }
        if (!bt) {
            int kr = t >> 4;
            int nn = (t & 15) * 4;
            int col = n0 + nn;
            float4 b4;
            if ((col + 3 < N) && ((ldb & 3) == 0)) {
                b4 = *(const float4*)&Bm[(size_t)(k0 + kr) * ldb + col];
            } else {
                b4.x = (col + 0 < N) ? Bm[(size_t)(k0 + kr) * ldb + col + 0] : 0.f;
                b4.y = (col + 1 < N) ? Bm[(size_t)(k0 + kr) * ldb + col + 1] : 0.f;
                b4.z = (col + 2 < N) ? Bm[(size_t)(k0 + kr) * ldb + col + 2] : 0.f;
                b4.w = (col + 3 < N) ? Bm[(size_t)(k0 + kr) * ldb + col + 3] : 0.f;
            }
            *(float4*)&Bs[kr][nn] = b4;
        } else {
            int nn = t >> 2;
            int kq = (t & 3) * 4;
            int col = n0 + nn;
            float4 b4 = {0.f, 0.f, 0.f, 0.f};
            if (col < N) b4 = *(const float4*)&Bm[(size_t)col * ldb + k0 + kq];
            Bs[kq + 0][nn] = b4.x;
            Bs[kq + 1][nn] = b4.y;
            Bs[kq + 2][nn] = b4.z;
            Bs[kq + 3][nn] = b4.w;
        }
        __syncthreads();
#pragma unroll
        for (int kk = 0; kk < 16; ++kk) {
            float4 a0 = *(const float4*)&As[kk][ty * 8];
            float4 a1 = *(const float4*)&As[kk][ty * 8 + 4];
            float4 b4 = *(const float4*)&Bs[kk][tx * 4];
            float av[8] = {a0.x, a0.y, a0.z, a0.w, a1.x, a1.y, a1.z, a1.w};
            float bv2[4] = {b4.x, b4.y, b4.z, b4.w};
#pragma unroll
            for (int i = 0; i < 8; ++i)
#pragma unroll
                for (int j = 0; j < 4; ++j) acc[i][j] += av[i] * bv2[j];
        }
        __syncthreads();
    }
    float scl = (act == 2) ? *sclp : 0.f;
#pragma unroll
    for (int i = 0; i < 8; ++i) {
        int row = m0 + ty * 8 + i;
#pragma unroll
        for (int j = 0; j < 4; ++j) {
            int col = n0 + tx * 4 + j;
            if (col < N) {
                float v = acc[i][j];
                if (bias) v += bias[col];
                if (act == 1) v = fmaxf(v, 0.f);
                else if (act == 2) v = tanhf(v) * scl;
                C[(size_t)row * ldc + col] = v;
            }
        }
    }
}

// ---------------- fused sample + scores + softmax + aggregate (two-pass) ----------
// 1 block = 1 query, 2 waves. Wave w owns channels [w*128, w*128+128).
// Phase A: lane = sample k (<49): gather bf16 corners over wave's 128 ch,
//          accumulate 8 partial head scores. Exchange partials via 4KB LDS.
// Phase B: lane = channel pair; coalesced re-gather of corner rows, aggregate
//          with softmaxed weights (shuffled from lane k).
__global__ __launch_bounds__(128) void k2_attn(
    const __hip_bfloat16* __restrict__ memT, const float* __restrict__ refb,
    const float* __restrict__ OFFb, const float* __restrict__ QKb,
    float* __restrict__ AGG, float* __restrict__ attnOut) {
    __shared__ float px[2][8][64];
    const int wid = threadIdx.x >> 6;
    const int lane = threadIdx.x & 63;
    int bid = blockIdx.x;
    // XCD swizzle: 4096 blocks -> 8 chunks of 512 (each XCD caches one batch-half)
    const int qu = __builtin_amdgcn_readfirstlane((bid & 7) * 512 + (bid >> 3));
    const int b = qu >> 10, n = qu & 1023;

    const float cx = refb[(size_t)qu * 4 + 0] * 2.f - 1.f;
    const float cy = refb[(size_t)qu * 4 + 1] * 2.f - 1.f;
    const bool act = lane < KK;
    float ox = 0.f, oy = 0.f;
    if (act) {
        float2 o2 = *(const float2*)&OFFb[(size_t)qu * 98 + 2 * lane];
        ox = o2.x;
        oy = o2.y;
    }
    int gxk = lane % 7, gyk = (lane / 7) % 7;
    float sx = fminf(fmaxf(cx + (float)(gxk - 3) * (2.f / 63.f) + ox, -1.f), 1.f);
    float sy = fminf(fmaxf(cy + (float)(gyk - 3) * (2.f / 63.f) + oy, -1.f), 1.f);
    float xf = (sx + 1.f) * 31.5f, yf = (sy + 1.f) * 31.5f;
    float x0f = floorf(xf), y0f = floorf(yf);
    float fx = xf - x0f, fy = yf - y0f;
    int x0 = min(max((int)x0f, 0), 63), y0 = min(max((int)y0f, 0), 63);
    int x1 = min(x0 + 1, 63), y1 = min(y0 + 1, 63);
    const int r00 = y0 * 64 + x0;
    float w00 = (1.f - fx) * (1.f - fy), w01 = fx * (1.f - fy);
    float w10 = (1.f - fx) * fy, w11 = fx * fy;

    const __hip_bfloat16* mb = memT + (size_t)b * HWP * DM;
    const float* qk = QKb + (size_t)qu * 2048 + wid * 128;
    float p[8];
#pragma unroll
    for (int h = 0; h < 8; ++h) p[h] = 0.f;

    if (act) {
        const __hip_bfloat16* p00 = mb + (size_t)(y0 * 64 + x0) * DM + wid * 128;
        const __hip_bfloat16* p01 = mb + (size_t)(y0 * 64 + x1) * DM + wid * 128;
        const __hip_bfloat16* p10 = mb + (size_t)(y1 * 64 + x0) * DM + wid * 128;
        const __hip_bfloat16* p11 = mb + (size_t)(y1 * 64 + x1) * DM + wid * 128;
#pragma unroll 4
        for (int cc = 0; cc < 128; cc += 8) {
            uint4 u00 = *(const uint4*)(p00 + cc);
            uint4 u01 = *(const uint4*)(p01 + cc);
            uint4 u10 = *(const uint4*)(p10 + cc);
            uint4 u11 = *(const uint4*)(p11 + cc);
            const unsigned* a00 = (const unsigned*)&u00;
            const unsigned* a01 = (const unsigned*)&u01;
            const unsigned* a10 = (const unsigned*)&u10;
            const unsigned* a11 = (const unsigned*)&u11;
            float s[8];
#pragma unroll
            for (int q = 0; q < 4; ++q) {
                s[2 * q] = w00 * bflo(a00[q]) + w01 * bflo(a01[q]) +
                           w10 * bflo(a10[q]) + w11 * bflo(a11[q]);
                s[2 * q + 1] = w00 * bfhi(a00[q]) + w01 * bfhi(a01[q]) +
                               w10 * bfhi(a10[q]) + w11 * bfhi(a11[q]);
            }
#pragma unroll
            for (int h = 0; h < 8; ++h) {
                const float* qr = qk + h * 256 + cc;
                float4 qa = *(const float4*)qr;
                float4 qb2 = *(const float4*)(qr + 4);
                p[h] += s[0] * qa.x + s[1] * qa.y + s[2] * qa.z + s[3] * qa.w +
                        s[4] * qb2.x + s[5] * qb2.y + s[6] * qb2.z + s[7] * qb2.w;
            }
        }
    }

    // exchange partial scores across the two waves
#pragma unroll
    for (int h = 0; h < 8; ++h) px[wid][h][lane] = p[h];
    __syncthreads();
#pragma unroll
    for (int h = 0; h < 8; ++h) p[h] = px[0][h][lane] + px[1][h][lane];

    // softmax over k (lanes), per head
    const float scl = 0.17677669529663687f;  // 1/sqrt(32)
    float attn[8];
#pragma unroll
    for (int h = 0; h < 8; ++h) {
        float s = act ? p[h] * scl : -INFINITY;
        float m = s;
#pragma unroll
        for (int off = 32; off; off >>= 1) m = fmaxf(m, __shfl_xor(m, off));
        float e = act ? __expf(s - m) : 0.f;
        float sum = e;
#pragma unroll
        for (int off = 32; off; off >>= 1) sum += __shfl_xor(sum, off);
        attn[h] = e / sum;
    }
    if (wid == 0 && act) {
#pragma unroll
        for (int h = 0; h < 8; ++h)
            attnOut[((size_t)(b * 8 + h) * 1024 + n) * 49 + lane] = attn[h];
    }

    // Phase B: lane owns channel pair c2..c2+1; coalesced row loads
    const int c2 = wid * 128 + lane * 2;
    const __hip_bfloat16* mc = mb + c2;
    float accA[8], accB[8];
#pragma unroll
    for (int h = 0; h < 8; ++h) accA[h] = accB[h] = 0.f;
#pragma unroll 7
    for (int k = 0; k < KK; ++k) {
        int rr = __shfl(r00, k);
        float kfx = __shfl(fx, k), kfy = __shfl(fy, k);
        int x0k = rr & 63, y0k = rr >> 6;
        int x1k = min(x0k + 1, 63), y1k = min(y0k + 1, 63);
        unsigned d00 = *(const unsigned*)(mc + (size_t)(y0k * 64 + x0k) * DM);
        unsigned d01 = *(const unsigned*)(mc + (size_t)(y0k * 64 + x1k) * DM);
        unsigned d10 = *(const unsigned*)(mc + (size_t)(y1k * 64 + x0k) * DM);
        unsigned d11 = *(const unsigned*)(mc + (size_t)(y1k * 64 + x1k) * DM);
        float kw00 = (1.f - kfx) * (1.f - kfy), kw01 = kfx * (1.f - kfy);
        float kw10 = (1.f - kfx) * kfy, kw11 = kfx * kfy;
        float sa = kw00 * bflo(d00) + kw01 * bflo(d01) + kw10 * bflo(d10) + kw11 * bflo(d11);
        float sb = kw00 * bfhi(d00) + kw01 * bfhi(d01) + kw10 * bfhi(d10) + kw11 * bfhi(d11);
#pragma unroll
        for (int h = 0; h < 8; ++h) {
            float av = __shfl(attn[h], k);
            accA[h] += av * sa;
            accB[h] += av * sb;
        }
    }
    float* ag = AGG + (size_t)qu * 2048;
#pragma unroll
    for (int h = 0; h < 8; ++h) {
        float2 st;
        st.x = accA[h];
        st.y = accB[h];
        *(float2*)&ag[h * 256 + c2] = st;
    }
}

extern "C" void kernel_launch(void* const* d_in, const int* in_sizes, int n_in,
                              void* d_out, int out_size, void* d_ws, size_t ws_size,
                              hipStream_t stream) {
    (void)in_sizes; (void)n_in; (void)out_size; (void)ws_size;
    const float* X     = (const float*)d_in[0];
    const float* refb  = (const float*)d_in[1];
    const float* mem   = (const float*)d_in[2];
    const float* Wq    = (const float*)d_in[3];
    const float* bq    = (const float*)d_in[4];
    const float* Wk    = (const float*)d_in[5];
    const float* Wv    = (const float*)d_in[7];
    const float* bv    = (const float*)d_in[8];
    const float* Wo    = (const float*)d_in[9];
    const float* bo    = (const float*)d_in[10];
    const float* Woff1 = (const float*)d_in[11];
    const float* boff1 = (const float*)d_in[12];
    const float* Woff2 = (const float*)d_in[13];
    const float* boff2 = (const float*)d_in[14];
    const float* sigma = (const float*)d_in[15];

    float* out  = (float*)d_out;
    float* attn = out + (size_t)BB * NQ1 * DM;  // (B,8,N,49)

    float* ws = (float*)d_ws;
    __hip_bfloat16* memT = (__hip_bfloat16*)ws;  // 4,194,304 bf16 = 2,097,152 f32 slots
    float* Qb   = ws + 2097152;        // 1,048,576
    float* Hb   = ws + 3145728;        // 1,048,576
    float* OFFb = ws + 4194304;        //   401,408
    float* QKb  = ws + 4595712;        // 8,388,608
    float* AGGb = ws + 12984320;       // 8,388,608
    float* OHb  = ws + 21372928;       // 1,048,576  (total ~90 MB)

    // 1) memory transpose -> bf16 (B,HW,C)
    k_transpose<<<dim3(128, 8, 4), dim3(32, 8), 0, stream>>>(mem, memT);
    // 2) Q = X@Wq + bq
    gemm_f32<<<dim3(4, 32, 1), 256, 0, stream>>>(X, Wq, bq, Qb,
        NQT, 256, 256, 256, 256, 256, 0, 0, 0, 0, nullptr, 0, 0);
    // 3) H = relu(X@Woff1 + boff1)
    gemm_f32<<<dim3(4, 32, 1), 256, 0, stream>>>(X, Woff1, boff1, Hb,
        NQT, 256, 256, 256, 256, 256, 0, 0, 0, 0, nullptr, 1, 0);
    // 4) OFF = tanh(H@Woff2 + boff2)*sigma   (N=98)
    gemm_f32<<<dim3(2, 32, 1), 256, 0, stream>>>(Hb, Woff2, boff2, OFFb,
        NQT, 98, 256, 256, 98, 98, 0, 0, 0, 0, sigma, 2, 0);
    // 5) QK[n, h*256+c] = sum_j Q[n,h*32+j]*Wk[c,h*32+j]   (batched over h, B^T)
    gemm_f32<<<dim3(4, 32, 8), 256, 0, stream>>>(Qb, Wk, nullptr, QKb,
        NQT, 256, 32, 256, 256, 2048, 32, 32, 256, 0, nullptr, 0, 1);
    // 6) fused sampling + scores + softmax + aggregate
    k2_attn<<<4096, 128, 0, stream>>>(memT, refb, OFFb, QKb, AGGb, attn);
    // 7) OH[n, h*32+j] = sum_c AGG[n,h*256+c]*Wv[c,h*32+j] + bv  (batched, N=32)
    gemm_f32<<<dim3(1, 32, 8), 256, 0, stream>>>(AGGb, Wv, bv, OHb,
        NQT, 32, 256, 2048, 256, 256, 256, 32, 32, 32, nullptr, 0, 0);
    // 8) out = OH@Wo + bo
    gemm_f32<<<dim3(4, 32, 1), 256, 0, stream>>>(OHb, Wo, bo, out,
        NQT, 256, 256, 256, 256, 256, 0, 0, 0, 0, nullptr, 0, 0);
}

// Round 4
// 268.206 us; speedup vs baseline: 1.6299x; 1.6299x over previous
//
#include <hip/hip_runtime.h>
#include <hip/hip_bf16.h>
#include <math.h>

#define DEV __device__ __forceinline__

typedef __attribute__((ext_vector_type(8))) short bf16x8;
typedef __attribute__((ext_vector_type(4))) float f32x4;

constexpr int BB = 4, NQ1 = 1024, DM = 256, KK = 49;
constexpr int HWP = 4096;
constexpr int NQT = 4096;

DEV float bflo(unsigned u) { return __uint_as_float(u << 16); }
DEV float bfhi(unsigned u) { return __uint_as_float(u & 0xffff0000u); }
DEV unsigned pack2(float a, float b) {
    __hip_bfloat162 h2;
    h2.x = __float2bfloat16(a);
    h2.y = __float2bfloat16(b);
    unsigned u;
    __builtin_memcpy(&u, &h2, 4);
    return u;
}
DEV ushort f2bf(float a) {
    __hip_bfloat16 h = __float2bfloat16(a);
    ushort u;
    __builtin_memcpy(&u, &h, 2);
    return u;
}

// ---------------- cast X -> bf16 ----------------
__global__ __launch_bounds__(256) void k_cast(const float* __restrict__ src,
                                              ushort* __restrict__ dst) {
    int i = (blockIdx.x * 256 + threadIdx.x) * 8;
    float4 a = *(const float4*)&src[i];
    float4 b = *(const float4*)&src[i + 4];
    uint4 pk;
    pk.x = pack2(a.x, a.y);
    pk.y = pack2(a.z, a.w);
    pk.z = pack2(b.x, b.y);
    pk.w = pack2(b.z, b.w);
    *(uint4*)&dst[i] = pk;
}

// ---------------- transpose memory (B,C,H,W) -> memT (B,HW,C) bf16 ----------------
__global__ __launch_bounds__(256) void k_transpose(const float* __restrict__ src,
                                                   ushort* __restrict__ dst) {
    __shared__ float tile[32][33];
    int b = blockIdx.z;
    int c0 = blockIdx.y * 32;
    int p0 = blockIdx.x * 32;
    int tx = threadIdx.x, ty = threadIdx.y;
    const float* s = src + ((size_t)b * DM + c0) * HWP + p0;
#pragma unroll
    for (int i = 0; i < 32; i += 8) tile[ty + i][tx] = s[(size_t)(ty + i) * HWP + tx];
    __syncthreads();
    ushort* d = dst + ((size_t)b * HWP + p0) * DM + c0;
#pragma unroll
    for (int i = 0; i < 32; i += 8)
        d[(size_t)(ty + i) * DM + tx] = f2bf(tile[tx][ty + i]);
}

// ---------------- transpose+cast weight: src f32 [K][N] -> dst bf16 [N][K] -------
__global__ __launch_bounds__(256) void k_transW(const float* __restrict__ src,
                                                ushort* __restrict__ dst, int K, int N) {
    __shared__ float tile[32][33];
    int n0 = blockIdx.x * 32, k0 = blockIdx.y * 32;
    int tx = threadIdx.x, ty = threadIdx.y;
#pragma unroll
    for (int i = 0; i < 32; i += 8)
        if (k0 + ty + i < K && n0 + tx < N)
            tile[ty + i][tx] = src[(size_t)(k0 + ty + i) * N + n0 + tx];
    __syncthreads();
#pragma unroll
    for (int i = 0; i < 32; i += 8)
        if (n0 + ty + i < N && k0 + tx < K)
            dst[(size_t)(n0 + ty + i) * K + k0 + tx] = f2bf(tile[tx][ty + i]);
}

// ---------------- Wqk_t[hc][d] = sum_j Wq[d][h*32+j] * Wk[c][h*32+j]; bqk -------
__global__ __launch_bounds__(256) void k_prep_wqk(
    const float* __restrict__ Wq, const float* __restrict__ Wk,
    const float* __restrict__ bq, ushort* __restrict__ Wqk_t,
    float* __restrict__ bqk) {
    __shared__ float wks[32];
    int hc = blockIdx.x;
    int h = hc >> 8, c = hc & 255;
    int t = threadIdx.x;
    if (t < 32) wks[t] = Wk[(size_t)c * 256 + h * 32 + t];
    __syncthreads();
    const float* wq = Wq + (size_t)t * 256 + h * 32;
    float acc = 0.f;
#pragma unroll
    for (int j = 0; j < 32; ++j) acc += wq[j] * wks[j];
    Wqk_t[(size_t)hc * 256 + t] = f2bf(acc);
    if (t == 0) {
        float bacc = 0.f;
#pragma unroll
        for (int j = 0; j < 32; ++j) bacc += bq[h * 32 + j] * wks[j];
        bqk[hc] = bacc;
    }
}

// --------- Wvo_t[e][hc] = sum_j Wv[c][h*32+j] * Wo[h*32+j][e]; bvo = bo + bv@Wo ---
__global__ __launch_bounds__(256) void k_prep_wvo(
    const float* __restrict__ Wv, const float* __restrict__ Wo,
    const float* __restrict__ bv, const float* __restrict__ bo,
    ushort* __restrict__ Wvo_t, float* __restrict__ bvo) {
    __shared__ float wos[256];
    int e = blockIdx.x;
    int t = threadIdx.x;
    wos[t] = Wo[(size_t)t * 256 + e];
    __syncthreads();
    for (int hc = t; hc < 2048; hc += 256) {
        int h = hc >> 8, c = hc & 255;
        const float* wv = Wv + (size_t)c * 256 + h * 32;
        const float* wo = &wos[h * 32];
        float acc = 0.f;
#pragma unroll
        for (int j = 0; j < 32; ++j) acc += wv[j] * wo[j];
        Wvo_t[(size_t)e * 2048 + hc] = f2bf(acc);
    }
    if (t == 0) {
        float bacc = bo[e];
#pragma unroll 8
        for (int d = 0; d < 256; ++d) bacc += bv[d] * wos[d];
        bvo[e] = bacc;
    }
}

// ---------------- bf16 MFMA GEMM: C = act(A[M][K] @ Bt[N][K]^T + bias) -----------
// 256 threads = 4 waves (2x2). TM in {64,128}, TN = 64. K % 32 == 0.
// ACT: 0 none, 1 relu, 2 tanh*(*sclp). OUTBF: 1 -> bf16 out, 0 -> f32 out.
template <int TM, int TN, int ACT, int OUTBF>
__global__ __launch_bounds__(256) void gemm_bf16(
    const ushort* __restrict__ A, const ushort* __restrict__ Bt,
    const float* __restrict__ bias, void* __restrict__ Cout,
    int N, int K, int ldc, const float* __restrict__ sclp) {
    __shared__ ushort As[TM][32];
    __shared__ ushort Bs[TN][32];
    const int t = threadIdx.x;
    const int lane = t & 63, wid = t >> 6;
    const int wr = wid >> 1, wc = wid & 1;
    const int m0 = blockIdx.y * TM, n0 = blockIdx.x * TN;
    constexpr int FM = TM / 32, FN = TN / 32;
    f32x4 acc[FM][FN];
#pragma unroll
    for (int i = 0; i < FM; ++i)
#pragma unroll
        for (int j = 0; j < FN; ++j) acc[i][j] = (f32x4){0.f, 0.f, 0.f, 0.f};

    const int l15 = lane & 15, lkg = lane >> 4;

    for (int k0 = 0; k0 < K; k0 += 32) {
        if constexpr (TM == 128) {
            int m = t >> 1, kc = (t & 1) * 16;
            const ushort* ap = &A[(size_t)(m0 + m) * K + k0 + kc];
            *(uint4*)&As[m][kc] = *(const uint4*)ap;
            *(uint4*)&As[m][kc + 8] = *(const uint4*)(ap + 8);
        } else {
            int m = t >> 2, kc = (t & 3) * 8;
            *(uint4*)&As[m][kc] = *(const uint4*)&A[(size_t)(m0 + m) * K + k0 + kc];
        }
        {
            int nn = t >> 2, kc = (t & 3) * 8;
            uint4 v = {0u, 0u, 0u, 0u};
            if (n0 + nn < N) v = *(const uint4*)&Bt[(size_t)(n0 + nn) * K + k0 + kc];
            *(uint4*)&Bs[nn][kc] = v;
        }
        __syncthreads();
        bf16x8 af[FM], bfv[FN];
#pragma unroll
        for (int mi = 0; mi < FM; ++mi)
            af[mi] = *(const bf16x8*)&As[wr * (TM / 2) + mi * 16 + l15][lkg * 8];
#pragma unroll
        for (int ni = 0; ni < FN; ++ni)
            bfv[ni] = *(const bf16x8*)&Bs[wc * (TN / 2) + ni * 16 + l15][lkg * 8];
#pragma unroll
        for (int mi = 0; mi < FM; ++mi)
#pragma unroll
            for (int ni = 0; ni < FN; ++ni)
                acc[mi][ni] = __builtin_amdgcn_mfma_f32_16x16x32_bf16(
                    af[mi], bfv[ni], acc[mi][ni], 0, 0, 0);
        __syncthreads();
    }

    float scl = (ACT == 2) ? *sclp : 0.f;
#pragma unroll
    for (int mi = 0; mi < FM; ++mi)
#pragma unroll
        for (int ni = 0; ni < FN; ++ni) {
            int col = n0 + wc * (TN / 2) + ni * 16 + l15;
            if (col < N) {
                float bcol = bias[col];
#pragma unroll
                for (int i = 0; i < 4; ++i) {
                    int row = m0 + wr * (TM / 2) + mi * 16 + lkg * 4 + i;
                    float v = acc[mi][ni][i] + bcol;
                    if (ACT == 1) v = fmaxf(v, 0.f);
                    else if (ACT == 2) v = tanhf(v) * scl;
                    if (OUTBF)
                        ((ushort*)Cout)[(size_t)row * ldc + col] = f2bf(v);
                    else
                        ((float*)Cout)[(size_t)row * ldc + col] = v;
                }
            }
        }
}

// ---------------- fused sample + scores + softmax + aggregate -------------------
// 1 block = 1 query, 4 waves. Gather ONCE into LDS (wave w: ch [w*64,w*64+64)),
// wave w computes heads {2w,2w+1} from LDS, softmax, then lane=channel aggregate.
__global__ __launch_bounds__(256) void k2_attn(
    const ushort* __restrict__ memT, const float* __restrict__ refb,
    const float* __restrict__ OFFb, const float* __restrict__ QKb,
    ushort* __restrict__ AGG, float* __restrict__ attnOut) {
    __shared__ unsigned samp[49 * 132];   // bf16 pairs, row stride 132 dwords
    __shared__ float attnL[49][8];
    const int t = threadIdx.x;
    const int wid = t >> 6, lane = t & 63;
    const int qu = __builtin_amdgcn_readfirstlane((int)((blockIdx.x & 7) * 512 + (blockIdx.x >> 3)));
    const int b = qu >> 10, n = qu & 1023;
    const bool act = lane < KK;

    const float cx = refb[(size_t)qu * 4 + 0] * 2.f - 1.f;
    const float cy = refb[(size_t)qu * 4 + 1] * 2.f - 1.f;
    float ox = 0.f, oy = 0.f;
    if (act) {
        float2 o2 = *(const float2*)&OFFb[(size_t)qu * 98 + 2 * lane];
        ox = o2.x;
        oy = o2.y;
    }
    float sx = fminf(fmaxf(cx + (float)((lane % 7) - 3) * (2.f / 63.f) + ox, -1.f), 1.f);
    float sy = fminf(fmaxf(cy + (float)(((lane / 7) % 7) - 3) * (2.f / 63.f) + oy, -1.f), 1.f);
    float xf = (sx + 1.f) * 31.5f, yf = (sy + 1.f) * 31.5f;
    float x0f = floorf(xf), y0f = floorf(yf);
    float fx = xf - x0f, fy = yf - y0f;
    int x0 = min(max((int)x0f, 0), 63), y0 = min(max((int)y0f, 0), 63);
    int x1 = min(x0 + 1, 63), y1 = min(y0 + 1, 63);
    float w00 = (1.f - fx) * (1.f - fy), w01 = fx * (1.f - fy);
    float w10 = (1.f - fx) * fy, w11 = fx * fy;

    const ushort* mb = memT + (size_t)b * HWP * DM;

    // Phase A: gather 64-ch slice per wave, lerp, pack to LDS
    if (act) {
        const ushort* p00 = mb + (size_t)(y0 * 64 + x0) * DM + wid * 64;
        const ushort* p01 = mb + (size_t)(y0 * 64 + x1) * DM + wid * 64;
        const ushort* p10 = mb + (size_t)(y1 * 64 + x0) * DM + wid * 64;
        const ushort* p11 = mb + (size_t)(y1 * 64 + x1) * DM + wid * 64;
        unsigned* srow = &samp[lane * 132 + wid * 32];
#pragma unroll
        for (int cc = 0; cc < 64; cc += 8) {
            uint4 u00 = *(const uint4*)(p00 + cc);
            uint4 u01 = *(const uint4*)(p01 + cc);
            uint4 u10 = *(const uint4*)(p10 + cc);
            uint4 u11 = *(const uint4*)(p11 + cc);
            const unsigned* a00 = (const unsigned*)&u00;
            const unsigned* a01 = (const unsigned*)&u01;
            const unsigned* a10 = (const unsigned*)&u10;
            const unsigned* a11 = (const unsigned*)&u11;
            float s[8];
#pragma unroll
            for (int q = 0; q < 4; ++q) {
                s[2 * q] = w00 * bflo(a00[q]) + w01 * bflo(a01[q]) +
                           w10 * bflo(a10[q]) + w11 * bflo(a11[q]);
                s[2 * q + 1] = w00 * bfhi(a00[q]) + w01 * bfhi(a01[q]) +
                               w10 * bfhi(a10[q]) + w11 * bfhi(a11[q]);
            }
            uint4 pk;
            pk.x = pack2(s[0], s[1]);
            pk.y = pack2(s[2], s[3]);
            pk.z = pack2(s[4], s[5]);
            pk.w = pack2(s[6], s[7]);
            *(uint4*)&srow[cc / 2] = pk;
        }
    }
    __syncthreads();

    // Phase A2: wave wid -> heads 2*wid, 2*wid+1; full 256-ch dot from LDS
    const int qkoff = __builtin_amdgcn_readfirstlane(qu * 2048 + wid * 512);
    const float* qk0 = QKb + qkoff;
    float p0 = 0.f, p1 = 0.f;
    if (act) {
        const unsigned* srow = &samp[lane * 132];
#pragma unroll 8
        for (int cc = 0; cc < 256; cc += 8) {
            uint4 u = *(const uint4*)&srow[cc / 2];
            const unsigned* au = (const unsigned*)&u;
            float s[8];
#pragma unroll
            for (int q = 0; q < 4; ++q) {
                s[2 * q] = bflo(au[q]);
                s[2 * q + 1] = bfhi(au[q]);
            }
            float4 qa = *(const float4*)(qk0 + cc);
            float4 qb = *(const float4*)(qk0 + cc + 4);
            float4 qc = *(const float4*)(qk0 + 256 + cc);
            float4 qd = *(const float4*)(qk0 + 256 + cc + 4);
            p0 += s[0] * qa.x + s[1] * qa.y + s[2] * qa.z + s[3] * qa.w +
                  s[4] * qb.x + s[5] * qb.y + s[6] * qb.z + s[7] * qb.w;
            p1 += s[0] * qc.x + s[1] * qc.y + s[2] * qc.z + s[3] * qc.w +
                  s[4] * qd.x + s[5] * qd.y + s[6] * qd.z + s[7] * qd.w;
        }
    }
    const float scl = 0.17677669529663687f;  // 1/sqrt(32)
    float s0 = act ? p0 * scl : -INFINITY;
    float s1 = act ? p1 * scl : -INFINITY;
    float m0v = s0, m1v = s1;
#pragma unroll
    for (int off = 32; off; off >>= 1) {
        m0v = fmaxf(m0v, __shfl_xor(m0v, off));
        m1v = fmaxf(m1v, __shfl_xor(m1v, off));
    }
    float e0 = act ? __expf(s0 - m0v) : 0.f;
    float e1 = act ? __expf(s1 - m1v) : 0.f;
    float sum0 = e0, sum1 = e1;
#pragma unroll
    for (int off = 32; off; off >>= 1) {
        sum0 += __shfl_xor(sum0, off);
        sum1 += __shfl_xor(sum1, off);
    }
    float at0 = e0 / sum0, at1 = e1 / sum1;
    if (act) {
        attnL[lane][2 * wid] = at0;
        attnL[lane][2 * wid + 1] = at1;
        attnOut[((size_t)(b * 8 + 2 * wid) * 1024 + n) * 49 + lane] = at0;
        attnOut[((size_t)(b * 8 + 2 * wid + 1) * 1024 + n) * 49 + lane] = at1;
    }
    __syncthreads();

    // Phase B: thread = channel c; acc[h] = sum_k attn[k][h] * samp[k][c]
    const int c = t;
    float acc[8];
#pragma unroll
    for (int h = 0; h < 8; ++h) acc[h] = 0.f;
#pragma unroll 7
    for (int k = 0; k < KK; ++k) {
        unsigned d = samp[k * 132 + (c >> 1)];
        float sv = (c & 1) ? bfhi(d) : bflo(d);
        float4 a0 = *(const float4*)&attnL[k][0];
        float4 a1 = *(const float4*)&attnL[k][4];
        acc[0] += a0.x * sv;
        acc[1] += a0.y * sv;
        acc[2] += a0.z * sv;
        acc[3] += a0.w * sv;
        acc[4] += a1.x * sv;
        acc[5] += a1.y * sv;
        acc[6] += a1.z * sv;
        acc[7] += a1.w * sv;
    }
    ushort* ag = AGG + (size_t)qu * 2048 + c;
#pragma unroll
    for (int h = 0; h < 8; ++h) ag[h * 256] = f2bf(acc[h]);
}

extern "C" void kernel_launch(void* const* d_in, const int* in_sizes, int n_in,
                              void* d_out, int out_size, void* d_ws, size_t ws_size,
                              hipStream_t stream) {
    (void)in_sizes; (void)n_in; (void)out_size; (void)ws_size;
    const float* X     = (const float*)d_in[0];
    const float* refb  = (const float*)d_in[1];
    const float* mem   = (const float*)d_in[2];
    const float* Wq    = (const float*)d_in[3];
    const float* bq    = (const float*)d_in[4];
    const float* Wk    = (const float*)d_in[5];
    const float* Wv    = (const float*)d_in[7];
    const float* bv    = (const float*)d_in[8];
    const float* Wo    = (const float*)d_in[9];
    const float* bo    = (const float*)d_in[10];
    const float* Woff1 = (const float*)d_in[11];
    const float* boff1 = (const float*)d_in[12];
    const float* Woff2 = (const float*)d_in[13];
    const float* boff2 = (const float*)d_in[14];
    const float* sigma = (const float*)d_in[15];

    float* out  = (float*)d_out;
    float* attn = out + (size_t)NQT * DM;  // (B,8,N,49) f32

    float* ws = (float*)d_ws;
    ushort* memT  = (ushort*)(ws + 0);         // 4*4096*256 bf16
    ushort* Xbf   = (ushort*)(ws + 2097152);   // 4096*256 bf16
    ushort* WqkT  = (ushort*)(ws + 2621440);   // 2048*256 bf16
    float*  bqk   = ws + 2883584;              // 2048 f32
    ushort* WvoT  = (ushort*)(ws + 2885632);   // 256*2048 bf16
    float*  bvo   = ws + 3147776;              // 256 f32
    ushort* W1t   = (ushort*)(ws + 3148032);   // 256*256 bf16
    ushort* W2t   = (ushort*)(ws + 3180800);   // 98*256 bf16
    float*  QKb   = ws + 3193344;              // 4096*2048 f32
    ushort* Hbf   = (ushort*)(ws + 11581952);  // 4096*256 bf16
    float*  OFFb  = ws + 11844096;             // 4096*98 f32
    ushort* AGGb  = (ushort*)(ws + 12245504);  // 4096*2048 bf16  (end ~65.8 MB)

    // prep (weights + layout)
    k_cast<<<512, 256, 0, stream>>>(X, Xbf);
    k_transpose<<<dim3(128, 8, 4), dim3(32, 8), 0, stream>>>(mem, memT);
    k_prep_wqk<<<2048, 256, 0, stream>>>(Wq, Wk, bq, WqkT, bqk);
    k_prep_wvo<<<256, 256, 0, stream>>>(Wv, Wo, bv, bo, WvoT, bvo);
    k_transW<<<dim3(8, 8), dim3(32, 8), 0, stream>>>(Woff1, W1t, 256, 256);
    k_transW<<<dim3(4, 8), dim3(32, 8), 0, stream>>>(Woff2, W2t, 256, 98);

    // QK = X @ Wqk + bqk   (M=4096, N=2048, K=256) -> f32
    gemm_bf16<128, 64, 0, 0><<<dim3(32, 32), 256, 0, stream>>>(
        Xbf, WqkT, bqk, QKb, 2048, 256, 2048, nullptr);
    // H = relu(X @ Woff1 + boff1) -> bf16   (N=256, K=256)
    gemm_bf16<64, 64, 1, 1><<<dim3(4, 64), 256, 0, stream>>>(
        Xbf, W1t, boff1, Hbf, 256, 256, 256, nullptr);
    // OFF = tanh(H @ Woff2 + boff2) * sigma -> f32  (N=98, K=256)
    gemm_bf16<64, 64, 2, 0><<<dim3(2, 64), 256, 0, stream>>>(
        Hbf, W2t, boff2, OFFb, 98, 256, 98, sigma);

    // fused sampling + scores + softmax + aggregate
    k2_attn<<<4096, 256, 0, stream>>>(memT, refb, OFFb, QKb, AGGb, attn);

    // out = AGG @ Wvo + bvo  (M=4096, N=256, K=2048) -> f32
    gemm_bf16<64, 64, 0, 0><<<dim3(4, 64), 256, 0, stream>>>(
        AGGb, WvoT, bvo, out, 256, 2048, 256, nullptr);
}

// Round 6
// 255.007 us; speedup vs baseline: 1.7143x; 1.0518x over previous
//
#include <hip/hip_runtime.h>
#include <hip/hip_bf16.h>
#include <math.h>

#define DEV __device__ __forceinline__

typedef __attribute__((ext_vector_type(8))) short bf16x8;
typedef __attribute__((ext_vector_type(4))) float f32x4;

constexpr int BB = 4, NQ1 = 1024, DM = 256, KK = 49;
constexpr int HWP = 4096;
constexpr int NQT = 4096;

DEV float bflo(unsigned u) { return __uint_as_float(u << 16); }
DEV float bfhi(unsigned u) { return __uint_as_float(u & 0xffff0000u); }
DEV unsigned pack2(float a, float b) {
    __hip_bfloat162 h2;
    h2.x = __float2bfloat16(a);
    h2.y = __float2bfloat16(b);
    unsigned u;
    __builtin_memcpy(&u, &h2, 4);
    return u;
}
DEV ushort f2bf(float a) {
    __hip_bfloat16 h = __float2bfloat16(a);
    ushort u;
    __builtin_memcpy(&u, &h, 2);
    return u;
}

// ================= fused prep: cast X, transpose mem, fold weights =================
// job ranges (blockIdx.x):
//   [0,512)      cast X -> bf16
//   [512,4608)   transpose memory (B,C,H,W) -> (B,HW,C) bf16
//   [4608,6656)  Wqk_t[hc][d] + bqk
//   [6656,6912)  Wvo_t[e][hc] + bvo
//   [6912,6976)  transW Woff1 (256x256)
//   [6976,7008)  transW Woff2 (256x98)
__global__ __launch_bounds__(256) void k_prep(
    const float* __restrict__ X, ushort* __restrict__ Xbf,
    const float* __restrict__ mem, ushort* __restrict__ memT,
    const float* __restrict__ Wq, const float* __restrict__ Wk,
    const float* __restrict__ bq, ushort* __restrict__ WqkT, float* __restrict__ bqk,
    const float* __restrict__ Wv, const float* __restrict__ Wo,
    const float* __restrict__ bv, const float* __restrict__ bo,
    ushort* __restrict__ WvoT, float* __restrict__ bvo,
    const float* __restrict__ Woff1, ushort* __restrict__ W1t,
    const float* __restrict__ Woff2, ushort* __restrict__ W2t) {
    __shared__ float smem[32 * 33];
    const int blk = blockIdx.x;
    const int t = threadIdx.x;

    if (blk < 512) {  // cast X
        int i = (blk * 256 + t) * 8;
        float4 a = *(const float4*)&X[i];
        float4 b = *(const float4*)&X[i + 4];
        uint4 pk;
        pk.x = pack2(a.x, a.y);
        pk.y = pack2(a.z, a.w);
        pk.z = pack2(b.x, b.y);
        pk.w = pack2(b.z, b.w);
        *(uint4*)&Xbf[i] = pk;
    } else if (blk < 4608) {  // transpose memory
        int r = blk - 512;
        int p0 = (r & 127) * 32;
        int c0 = ((r >> 7) & 7) * 32;
        int b = r >> 10;
        int tx = t & 31, ty = t >> 5;
        float (*tile)[33] = (float(*)[33])smem;
        const float* s = mem + ((size_t)b * DM + c0) * HWP + p0;
#pragma unroll
        for (int i = 0; i < 32; i += 8) tile[ty + i][tx] = s[(size_t)(ty + i) * HWP + tx];
        __syncthreads();
        ushort* d = memT + ((size_t)b * HWP + p0) * DM + c0;
#pragma unroll
        for (int i = 0; i < 32; i += 8)
            d[(size_t)(ty + i) * DM + tx] = f2bf(tile[tx][ty + i]);
    } else if (blk < 6656) {  // Wqk fold
        int hc = blk - 4608;
        int h = hc >> 8, c = hc & 255;
        if (t < 32) smem[t] = Wk[(size_t)c * 256 + h * 32 + t];
        __syncthreads();
        const float* wq = Wq + (size_t)t * 256 + h * 32;
        float acc = 0.f;
#pragma unroll
        for (int j = 0; j < 32; ++j) acc += wq[j] * smem[j];
        WqkT[(size_t)hc * 256 + t] = f2bf(acc);
        if (t == 0) {
            float bacc = 0.f;
#pragma unroll
            for (int j = 0; j < 32; ++j) bacc += bq[h * 32 + j] * smem[j];
            bqk[hc] = bacc;
        }
    } else if (blk < 6912) {  // Wvo fold
        int e = blk - 6656;
        smem[t] = Wo[(size_t)t * 256 + e];
        __syncthreads();
        for (int hc = t; hc < 2048; hc += 256) {
            int h = hc >> 8, c = hc & 255;
            const float* wv = Wv + (size_t)c * 256 + h * 32;
            const float* wo = &smem[h * 32];
            float acc = 0.f;
#pragma unroll
            for (int j = 0; j < 32; ++j) acc += wv[j] * wo[j];
            WvoT[(size_t)e * 2048 + hc] = f2bf(acc);
        }
        if (t == 0) {
            float bacc = bo[e];
#pragma unroll 8
            for (int d = 0; d < 256; ++d) bacc += bv[d] * smem[d];
            bvo[e] = bacc;
        }
    } else {  // weight transposes
        const float* src;
        ushort* dst;
        int K = 256, N, r;
        if (blk < 6976) { r = blk - 6912; src = Woff1; dst = W1t; N = 256; }
        else            { r = blk - 6976; src = Woff2; dst = W2t; N = 98; }
        int nblk = (N + 31) / 32;
        int n0 = (r % nblk) * 32, k0 = (r / nblk) * 32;
        int tx = t & 31, ty = t >> 5;
        float (*tile)[33] = (float(*)[33])smem;
#pragma unroll
        for (int i = 0; i < 32; i += 8)
            if (n0 + tx < N) tile[ty + i][tx] = src[(size_t)(k0 + ty + i) * N + n0 + tx];
        __syncthreads();
#pragma unroll
        for (int i = 0; i < 32; i += 8)
            if (n0 + ty + i < N)
                dst[(size_t)(n0 + ty + i) * K + k0 + tx] = f2bf(tile[tx][ty + i]);
    }
}

// ---------------- bf16 MFMA GEMM: C = act(A[M][K] @ Bt[N][K]^T + bias) -----------
// 256 threads = 4 waves (2x2). XOR-swizzled LDS (16B slots) to kill the 8-way
// bank conflict of row-major fragment reads. BK in {32,64}.
template <int TM, int TN, int BK, int ACT, int OUTBF>
__global__ __launch_bounds__(256) void gemm_bf16(
    const ushort* __restrict__ A, const ushort* __restrict__ Bt,
    const float* __restrict__ bias, void* __restrict__ Cout,
    int N, int K, int ldc, const float* __restrict__ sclp) {
    constexpr int SL = BK / 8;  // 16B slots per row
    __shared__ ushort As[TM][BK];
    __shared__ ushort Bs[TN][BK];
    const int t = threadIdx.x;
    const int lane = t & 63, wid = t >> 6;
    const int wr = wid >> 1, wc = wid & 1;
    const int m0 = blockIdx.y * TM, n0 = blockIdx.x * TN;
    constexpr int FM = TM / 32, FN = TN / 32, KS = BK / 32;
    f32x4 acc[FM][FN];
#pragma unroll
    for (int i = 0; i < FM; ++i)
#pragma unroll
        for (int j = 0; j < FN; ++j) acc[i][j] = (f32x4){0.f, 0.f, 0.f, 0.f};

    const int l15 = lane & 15, lkg = lane >> 4;

    for (int k0 = 0; k0 < K; k0 += BK) {
        constexpr int NA = TM * SL / 256;
#pragma unroll
        for (int i = 0; i < NA; ++i) {
            int idx = t + i * 256;
            int m = idx / SL, sl = idx % SL;
            int ss = sl ^ ((m >> 1) & (SL - 1));
            *(uint4*)&As[m][ss * 8] = *(const uint4*)&A[(size_t)(m0 + m) * K + k0 + sl * 8];
        }
        constexpr int NB = TN * SL / 256;
#pragma unroll
        for (int i = 0; i < NB; ++i) {
            int idx = t + i * 256;
            int nn = idx / SL, sl = idx % SL;
            int ss = sl ^ ((nn >> 1) & (SL - 1));
            uint4 v = {0u, 0u, 0u, 0u};
            if (n0 + nn < N) v = *(const uint4*)&Bt[(size_t)(n0 + nn) * K + k0 + sl * 8];
            *(uint4*)&Bs[nn][ss * 8] = v;
        }
        __syncthreads();
#pragma unroll
        for (int ks = 0; ks < KS; ++ks) {
            bf16x8 af[FM], bfv[FN];
#pragma unroll
            for (int mi = 0; mi < FM; ++mi) {
                int R = wr * (TM / 2) + mi * 16 + l15;
                int ss = (lkg + ks * 4) ^ ((R >> 1) & (SL - 1));
                af[mi] = *(const bf16x8*)&As[R][ss * 8];
            }
#pragma unroll
            for (int ni = 0; ni < FN; ++ni) {
                int R = wc * (TN / 2) + ni * 16 + l15;
                int ss = (lkg + ks * 4) ^ ((R >> 1) & (SL - 1));
                bfv[ni] = *(const bf16x8*)&Bs[R][ss * 8];
            }
#pragma unroll
            for (int mi = 0; mi < FM; ++mi)
#pragma unroll
                for (int ni = 0; ni < FN; ++ni)
                    acc[mi][ni] = __builtin_amdgcn_mfma_f32_16x16x32_bf16(
                        af[mi], bfv[ni], acc[mi][ni], 0, 0, 0);
        }
        __syncthreads();
    }

    float scl = (ACT == 2) ? *sclp : 0.f;
#pragma unroll
    for (int mi = 0; mi < FM; ++mi)
#pragma unroll
        for (int ni = 0; ni < FN; ++ni) {
            int col = n0 + wc * (TN / 2) + ni * 16 + l15;
            if (col < N) {
                float bcol = bias[col];
#pragma unroll
                for (int i = 0; i < 4; ++i) {
                    int row = m0 + wr * (TM / 2) + mi * 16 + lkg * 4 + i;
                    float v = acc[mi][ni][i] + bcol;
                    if (ACT == 1) v = fmaxf(v, 0.f);
                    else if (ACT == 2) v = tanhf(v) * scl;
                    if (OUTBF)
                        ((ushort*)Cout)[(size_t)row * ldc + col] = f2bf(v);
                    else
                        ((float*)Cout)[(size_t)row * ldc + col] = v;
                }
            }
        }
}

// ---------------- fused sample + scores + softmax + aggregate -------------------
// 1 block = 1 query, 4 waves. Wave w gathers channels [w*64,w*64+64) ONCE,
// dots its slice against all 8 heads' QK inline (registers, scalar QK loads),
// exchanges bf16 partials via LDS, softmax (wave w -> heads 2w,2w+1),
// then lane=channel aggregate from the LDS sample tile.
__global__ __launch_bounds__(256) void k2_attn(
    const ushort* __restrict__ memT, const float* __restrict__ refb,
    const float* __restrict__ OFFb, const float* __restrict__ QKb,
    ushort* __restrict__ AGG, float* __restrict__ attnOut) {
    __shared__ unsigned samp[49 * 132];   // bf16 pairs, row stride 132 dwords
    __shared__ unsigned pxb[4][4][64];    // bf16-pair partial scores [wave][h/2][lane]
    __shared__ float attnL[49][8];
    const int t = threadIdx.x;
    const int wid = t >> 6, lane = t & 63;
    const int qu = __builtin_amdgcn_readfirstlane((int)((blockIdx.x & 7) * 512 + (blockIdx.x >> 3)));
    const int b = qu >> 10, n = qu & 1023;
    const bool act = lane < KK;

    const float cx = refb[(size_t)qu * 4 + 0] * 2.f - 1.f;
    const float cy = refb[(size_t)qu * 4 + 1] * 2.f - 1.f;
    float ox = 0.f, oy = 0.f;
    if (act) {
        float2 o2 = *(const float2*)&OFFb[(size_t)qu * 98 + 2 * lane];
        ox = o2.x;
        oy = o2.y;
    }
    float sx = fminf(fmaxf(cx + (float)((lane % 7) - 3) * (2.f / 63.f) + ox, -1.f), 1.f);
    float sy = fminf(fmaxf(cy + (float)(((lane / 7) % 7) - 3) * (2.f / 63.f) + oy, -1.f), 1.f);
    float xf = (sx + 1.f) * 31.5f, yf = (sy + 1.f) * 31.5f;
    float x0f = floorf(xf), y0f = floorf(yf);
    float fx = xf - x0f, fy = yf - y0f;
    int x0 = min(max((int)x0f, 0), 63), y0 = min(max((int)y0f, 0), 63);
    int x1 = min(x0 + 1, 63), y1 = min(y0 + 1, 63);
    float w00 = (1.f - fx) * (1.f - fy), w01 = fx * (1.f - fy);
    float w10 = (1.f - fx) * fy, w11 = fx * fy;

    const ushort* mb = memT + (size_t)b * HWP * DM;
    const float* qk0 = QKb + (size_t)__builtin_amdgcn_readfirstlane(qu * 2048 + wid * 64);

    float p[8];
#pragma unroll
    for (int h = 0; h < 8; ++h) p[h] = 0.f;

    // Phase A: gather + lerp + pack to LDS + inline partial dot (this wave's 64 ch)
    if (act) {
        const ushort* p00 = mb + (size_t)(y0 * 64 + x0) * DM + wid * 64;
        const ushort* p01 = mb + (size_t)(y0 * 64 + x1) * DM + wid * 64;
        const ushort* p10 = mb + (size_t)(y1 * 64 + x0) * DM + wid * 64;
        const ushort* p11 = mb + (size_t)(y1 * 64 + x1) * DM + wid * 64;
        unsigned* srow = &samp[lane * 132 + wid * 32];
#pragma unroll 2
        for (int cc = 0; cc < 64; cc += 8) {
            uint4 u00 = *(const uint4*)(p00 + cc);
            uint4 u01 = *(const uint4*)(p01 + cc);
            uint4 u10 = *(const uint4*)(p10 + cc);
            uint4 u11 = *(const uint4*)(p11 + cc);
            const unsigned* a00 = (const unsigned*)&u00;
            const unsigned* a01 = (const unsigned*)&u01;
            const unsigned* a10 = (const unsigned*)&u10;
            const unsigned* a11 = (const unsigned*)&u11;
            float s[8];
#pragma unroll
            for (int q = 0; q < 4; ++q) {
                s[2 * q] = w00 * bflo(a00[q]) + w01 * bflo(a01[q]) +
                           w10 * bflo(a10[q]) + w11 * bflo(a11[q]);
                s[2 * q + 1] = w00 * bfhi(a00[q]) + w01 * bfhi(a01[q]) +
                               w10 * bfhi(a10[q]) + w11 * bfhi(a11[q]);
            }
            uint4 pk;
            pk.x = pack2(s[0], s[1]);
            pk.y = pack2(s[2], s[3]);
            pk.z = pack2(s[4], s[5]);
            pk.w = pack2(s[6], s[7]);
            *(uint4*)&srow[cc / 2] = pk;
#pragma unroll
            for (int h = 0; h < 8; ++h) {
                float4 qa = *(const float4*)(qk0 + h * 256 + cc);
                float4 qb = *(const float4*)(qk0 + h * 256 + cc + 4);
                p[h] += s[0] * qa.x + s[1] * qa.y + s[2] * qa.z + s[3] * qa.w +
                        s[4] * qb.x + s[5] * qb.y + s[6] * qb.z + s[7] * qb.w;
            }
        }
#pragma unroll
        for (int hp = 0; hp < 4; ++hp)
            pxb[wid][hp][lane] = pack2(p[2 * hp], p[2 * hp + 1]);
    }
    __syncthreads();

    // softmax: wave wid handles heads 2*wid, 2*wid+1 (= head-pair hp = wid)
    float p0 = 0.f, p1 = 0.f;
    if (act) {
#pragma unroll
        for (int w = 0; w < 4; ++w) {
            unsigned u = pxb[w][wid][lane];
            p0 += bflo(u);
            p1 += bfhi(u);
        }
    }
    const float scl = 0.17677669529663687f;  // 1/sqrt(32)
    float s0 = act ? p0 * scl : -INFINITY;
    float s1 = act ? p1 * scl : -INFINITY;
    float m0v = s0, m1v = s1;
#pragma unroll
    for (int off = 32; off; off >>= 1) {
        m0v = fmaxf(m0v, __shfl_xor(m0v, off));
        m1v = fmaxf(m1v, __shfl_xor(m1v, off));
    }
    float e0 = act ? __expf(s0 - m0v) : 0.f;
    float e1 = act ? __expf(s1 - m1v) : 0.f;
    float sum0 = e0, sum1 = e1;
#pragma unroll
    for (int off = 32; off; off >>= 1) {
        sum0 += __shfl_xor(sum0, off);
        sum1 += __shfl_xor(sum1, off);
    }
    float at0 = e0 / sum0, at1 = e1 / sum1;
    if (act) {
        attnL[lane][2 * wid] = at0;
        attnL[lane][2 * wid + 1] = at1;
        attnOut[((size_t)(b * 8 + 2 * wid) * 1024 + n) * 49 + lane] = at0;
        attnOut[((size_t)(b * 8 + 2 * wid + 1) * 1024 + n) * 49 + lane] = at1;
    }
    __syncthreads();

    // Phase B: thread = channel c; acc[h] = sum_k attn[k][h] * samp[k][c]
    const int c = t;
    float acc[8];
#pragma unroll
    for (int h = 0; h < 8; ++h) acc[h] = 0.f;
#pragma unroll 7
    for (int k = 0; k < KK; ++k) {
        unsigned d = samp[k * 132 + (c >> 1)];
        float sv = (c & 1) ? bfhi(d) : bflo(d);
        float4 a0 = *(const float4*)&attnL[k][0];
        float4 a1 = *(const float4*)&attnL[k][4];
        acc[0] += a0.x * sv;
        acc[1] += a0.y * sv;
        acc[2] += a0.z * sv;
        acc[3] += a0.w * sv;
        acc[4] += a1.x * sv;
        acc[5] += a1.y * sv;
        acc[6] += a1.z * sv;
        acc[7] += a1.w * sv;
    }
    ushort* ag = AGG + (size_t)qu * 2048 + c;
#pragma unroll
    for (int h = 0; h < 8; ++h) ag[h * 256] = f2bf(acc[h]);
}

extern "C" void kernel_launch(void* const* d_in, const int* in_sizes, int n_in,
                              void* d_out, int out_size, void* d_ws, size_t ws_size,
                              hipStream_t stream) {
    (void)in_sizes; (void)n_in; (void)out_size; (void)ws_size;
    const float* X     = (const float*)d_in[0];
    const float* refb  = (const float*)d_in[1];
    const float* mem   = (const float*)d_in[2];
    const float* Wq    = (const float*)d_in[3];
    const float* bq    = (const float*)d_in[4];
    const float* Wk    = (const float*)d_in[5];
    const float* Wv    = (const float*)d_in[7];
    const float* bv    = (const float*)d_in[8];
    const float* Wo    = (const float*)d_in[9];
    const float* bo    = (const float*)d_in[10];
    const float* Woff1 = (const float*)d_in[11];
    const float* boff1 = (const float*)d_in[12];
    const float* Woff2 = (const float*)d_in[13];
    const float* boff2 = (const float*)d_in[14];
    const float* sigma = (const float*)d_in[15];

    float* out  = (float*)d_out;
    float* attn = out + (size_t)NQT * DM;  // (B,8,N,49) f32

    float* ws = (float*)d_ws;
    ushort* memT  = (ushort*)(ws + 0);         // 4*4096*256 bf16
    ushort* Xbf   = (ushort*)(ws + 2097152);   // 4096*256 bf16
    ushort* WqkT  = (ushort*)(ws + 2621440);   // 2048*256 bf16
    float*  bqk   = ws + 2883584;              // 2048 f32
    ushort* WvoT  = (ushort*)(ws + 2885632);   // 256*2048 bf16
    float*  bvo   = ws + 3147776;              // 256 f32
    ushort* W1t   = (ushort*)(ws + 3148032);   // 256*256 bf16
    ushort* W2t   = (ushort*)(ws + 3180800);   // 98*256 bf16
    float*  QKb   = ws + 3193344;              // 4096*2048 f32
    ushort* Hbf   = (ushort*)(ws + 11581952);  // 4096*256 bf16
    float*  OFFb  = ws + 11844096;             // 4096*98 f32
    ushort* AGGb  = (ushort*)(ws + 12245504);  // 4096*2048 bf16  (end ~65.8 MB)

    // fused prep (cast, transposes, weight folds) — 1 dispatch
    k_prep<<<7008, 256, 0, stream>>>(X, Xbf, mem, memT, Wq, Wk, bq, WqkT, bqk,
                                     Wv, Wo, bv, bo, WvoT, bvo, Woff1, W1t, Woff2, W2t);

    // QK = X @ Wqk + bqk   (M=4096, N=2048, K=256) -> f32
    gemm_bf16<128, 64, 32, 0, 0><<<dim3(32, 32), 256, 0, stream>>>(
        Xbf, WqkT, bqk, QKb, 2048, 256, 2048, nullptr);
    // H = relu(X @ Woff1 + boff1) -> bf16   (N=256, K=256)
    gemm_bf16<64, 64, 32, 1, 1><<<dim3(4, 64), 256, 0, stream>>>(
        Xbf, W1t, boff1, Hbf, 256, 256, 256, nullptr);
    // OFF = tanh(H @ Woff2 + boff2) * sigma -> f32  (N=98, K=256)
    gemm_bf16<64, 64, 32, 2, 0><<<dim3(2, 64), 256, 0, stream>>>(
        Hbf, W2t, boff2, OFFb, 98, 256, 98, sigma);

    // fused sampling + scores + softmax + aggregate
    k2_attn<<<4096, 256, 0, stream>>>(memT, refb, OFFb, QKb, AGGb, attn);

    // out = AGG @ Wvo + bvo  (M=4096, N=256, K=2048) -> f32
    gemm_bf16<64, 64, 64, 0, 0><<<dim3(4, 64), 256, 0, stream>>>(
        AGGb, WvoT, bvo, out, 256, 2048, 256, nullptr);
}

// Round 7
// 250.230 us; speedup vs baseline: 1.7470x; 1.0191x over previous
//
#include <hip/hip_runtime.h>
#include <hip/hip_bf16.h>
#include <math.h>

#define DEV __device__ __forceinline__

typedef __attribute__((ext_vector_type(8))) short bf16x8;
typedef __attribute__((ext_vector_type(4))) float f32x4;

constexpr int BB = 4, NQ1 = 1024, DM = 256, KK = 49;
constexpr int HWP = 4096;
constexpr int NQT = 4096;

DEV float bflo(unsigned u) { return __uint_as_float(u << 16); }
DEV float bfhi(unsigned u) { return __uint_as_float(u & 0xffff0000u); }
DEV unsigned pack2(float a, float b) {
    __hip_bfloat162 h2;
    h2.x = __float2bfloat16(a);
    h2.y = __float2bfloat16(b);
    unsigned u;
    __builtin_memcpy(&u, &h2, 4);
    return u;
}
DEV ushort f2bf(float a) {
    __hip_bfloat16 h = __float2bfloat16(a);
    ushort u;
    __builtin_memcpy(&u, &h, 2);
    return u;
}

// ================= fused prep: cast X, transpose mem, fold weights =================
// job ranges (blockIdx.x):
//   [0,512)      cast X -> bf16
//   [512,4608)   transpose memory (B,C,H,W) -> (B,HW,C) bf16
//   [4608,6656)  Wqk_t[hc][d] + bqk
//   [6656,6912)  Wvo_t[e][hc] + bvo
//   [6912,6976)  transW Woff1 (256x256)
//   [6976,7008)  transW Woff2 (256x98)
__global__ __launch_bounds__(256) void k_prep(
    const float* __restrict__ X, ushort* __restrict__ Xbf,
    const float* __restrict__ mem, ushort* __restrict__ memT,
    const float* __restrict__ Wq, const float* __restrict__ Wk,
    const float* __restrict__ bq, ushort* __restrict__ WqkT, float* __restrict__ bqk,
    const float* __restrict__ Wv, const float* __restrict__ Wo,
    const float* __restrict__ bv, const float* __restrict__ bo,
    ushort* __restrict__ WvoT, float* __restrict__ bvo,
    const float* __restrict__ Woff1, ushort* __restrict__ W1t,
    const float* __restrict__ Woff2, ushort* __restrict__ W2t) {
    __shared__ float smem[32 * 33];
    const int blk = blockIdx.x;
    const int t = threadIdx.x;

    if (blk < 512) {  // cast X
        int i = (blk * 256 + t) * 8;
        float4 a = *(const float4*)&X[i];
        float4 b = *(const float4*)&X[i + 4];
        uint4 pk;
        pk.x = pack2(a.x, a.y);
        pk.y = pack2(a.z, a.w);
        pk.z = pack2(b.x, b.y);
        pk.w = pack2(b.z, b.w);
        *(uint4*)&Xbf[i] = pk;
    } else if (blk < 4608) {  // transpose memory
        int r = blk - 512;
        int p0 = (r & 127) * 32;
        int c0 = ((r >> 7) & 7) * 32;
        int b = r >> 10;
        int tx = t & 31, ty = t >> 5;
        float (*tile)[33] = (float(*)[33])smem;
        const float* s = mem + ((size_t)b * DM + c0) * HWP + p0;
#pragma unroll
        for (int i = 0; i < 32; i += 8) tile[ty + i][tx] = s[(size_t)(ty + i) * HWP + tx];
        __syncthreads();
        ushort* d = memT + ((size_t)b * HWP + p0) * DM + c0;
#pragma unroll
        for (int i = 0; i < 32; i += 8)
            d[(size_t)(ty + i) * DM + tx] = f2bf(tile[tx][ty + i]);
    } else if (blk < 6656) {  // Wqk fold
        int hc = blk - 4608;
        int h = hc >> 8, c = hc & 255;
        if (t < 32) smem[t] = Wk[(size_t)c * 256 + h * 32 + t];
        __syncthreads();
        const float* wq = Wq + (size_t)t * 256 + h * 32;
        float acc = 0.f;
#pragma unroll
        for (int j = 0; j < 32; ++j) acc += wq[j] * smem[j];
        WqkT[(size_t)hc * 256 + t] = f2bf(acc);
        if (t == 0) {
            float bacc = 0.f;
#pragma unroll
            for (int j = 0; j < 32; ++j) bacc += bq[h * 32 + j] * smem[j];
            bqk[hc] = bacc;
        }
    } else if (blk < 6912) {  // Wvo fold
        int e = blk - 6656;
        smem[t] = Wo[(size_t)t * 256 + e];
        __syncthreads();
        for (int hc = t; hc < 2048; hc += 256) {
            int h = hc >> 8, c = hc & 255;
            const float* wv = Wv + (size_t)c * 256 + h * 32;
            const float* wo = &smem[h * 32];
            float acc = 0.f;
#pragma unroll
            for (int j = 0; j < 32; ++j) acc += wv[j] * wo[j];
            WvoT[(size_t)e * 2048 + hc] = f2bf(acc);
        }
        if (t == 0) {
            float bacc = bo[e];
#pragma unroll 8
            for (int d = 0; d < 256; ++d) bacc += bv[d] * smem[d];
            bvo[e] = bacc;
        }
    } else {  // weight transposes
        const float* src;
        ushort* dst;
        int K = 256, N, r;
        if (blk < 6976) { r = blk - 6912; src = Woff1; dst = W1t; N = 256; }
        else            { r = blk - 6976; src = Woff2; dst = W2t; N = 98; }
        int nblk = (N + 31) / 32;
        int n0 = (r % nblk) * 32, k0 = (r / nblk) * 32;
        int tx = t & 31, ty = t >> 5;
        float (*tile)[33] = (float(*)[33])smem;
#pragma unroll
        for (int i = 0; i < 32; i += 8)
            if (n0 + tx < N) tile[ty + i][tx] = src[(size_t)(k0 + ty + i) * N + n0 + tx];
        __syncthreads();
#pragma unroll
        for (int i = 0; i < 32; i += 8)
            if (n0 + ty + i < N)
                dst[(size_t)(n0 + ty + i) * K + k0 + tx] = f2bf(tile[tx][ty + i]);
    }
}

// ---------------- bf16 MFMA GEMM: C = act(A[M][K] @ Bt[N][K]^T + bias) -----------
// 256 threads = 4 waves (2x2). XOR-swizzled LDS (16B slots). BK in {32,64}.
// TM in {64,128}, TN in {32,64}.
template <int TM, int TN, int BK, int ACT, int OUTBF>
__global__ __launch_bounds__(256) void gemm_bf16(
    const ushort* __restrict__ A, const ushort* __restrict__ Bt,
    const float* __restrict__ bias, void* __restrict__ Cout,
    int N, int K, int ldc, const float* __restrict__ sclp) {
    constexpr int SL = BK / 8;  // 16B slots per row
    __shared__ ushort As[TM][BK];
    __shared__ ushort Bs[TN][BK];
    const int t = threadIdx.x;
    const int lane = t & 63, wid = t >> 6;
    const int wr = wid >> 1, wc = wid & 1;
    const int m0 = blockIdx.y * TM, n0 = blockIdx.x * TN;
    constexpr int FM = TM / 32, FN = TN / 32, KS = BK / 32;
    f32x4 acc[FM][FN];
#pragma unroll
    for (int i = 0; i < FM; ++i)
#pragma unroll
        for (int j = 0; j < FN; ++j) acc[i][j] = (f32x4){0.f, 0.f, 0.f, 0.f};

    const int l15 = lane & 15, lkg = lane >> 4;

    for (int k0 = 0; k0 < K; k0 += BK) {
        constexpr int NA = TM * SL / 256;
#pragma unroll
        for (int i = 0; i < NA; ++i) {
            int idx = t + i * 256;
            int m = idx / SL, sl = idx % SL;
            int ss = sl ^ ((m >> 1) & (SL - 1));
            *(uint4*)&As[m][ss * 8] = *(const uint4*)&A[(size_t)(m0 + m) * K + k0 + sl * 8];
        }
        constexpr int NB = TN * SL / 256;
#pragma unroll
        for (int i = 0; i < NB; ++i) {
            int idx = t + i * 256;
            int nn = idx / SL, sl = idx % SL;
            int ss = sl ^ ((nn >> 1) & (SL - 1));
            uint4 v = {0u, 0u, 0u, 0u};
            if (n0 + nn < N) v = *(const uint4*)&Bt[(size_t)(n0 + nn) * K + k0 + sl * 8];
            *(uint4*)&Bs[nn][ss * 8] = v;
        }
        __syncthreads();
#pragma unroll
        for (int ks = 0; ks < KS; ++ks) {
            bf16x8 af[FM], bfv[FN];
#pragma unroll
            for (int mi = 0; mi < FM; ++mi) {
                int R = wr * (TM / 2) + mi * 16 + l15;
                int ss = (lkg + ks * 4) ^ ((R >> 1) & (SL - 1));
                af[mi] = *(const bf16x8*)&As[R][ss * 8];
            }
#pragma unroll
            for (int ni = 0; ni < FN; ++ni) {
                int R = wc * (TN / 2) + ni * 16 + l15;
                int ss = (lkg + ks * 4) ^ ((R >> 1) & (SL - 1));
                bfv[ni] = *(const bf16x8*)&Bs[R][ss * 8];
            }
#pragma unroll
            for (int mi = 0; mi < FM; ++mi)
#pragma unroll
                for (int ni = 0; ni < FN; ++ni)
                    acc[mi][ni] = __builtin_amdgcn_mfma_f32_16x16x32_bf16(
                        af[mi], bfv[ni], acc[mi][ni], 0, 0, 0);
        }
        __syncthreads();
    }

    float scl = (ACT == 2) ? *sclp : 0.f;
#pragma unroll
    for (int mi = 0; mi < FM; ++mi)
#pragma unroll
        for (int ni = 0; ni < FN; ++ni) {
            int col = n0 + wc * (TN / 2) + ni * 16 + l15;
            if (col < N) {
                float bcol = bias[col];
#pragma unroll
                for (int i = 0; i < 4; ++i) {
                    int row = m0 + wr * (TM / 2) + mi * 16 + lkg * 4 + i;
                    float v = acc[mi][ni][i] + bcol;
                    if (ACT == 1) v = fmaxf(v, 0.f);
                    else if (ACT == 2) v = tanhf(v) * scl;
                    if (OUTBF)
                        ((ushort*)Cout)[(size_t)row * ldc + col] = f2bf(v);
                    else
                        ((float*)Cout)[(size_t)row * ldc + col] = v;
                }
            }
        }
}

// ---------------- fused sample + scores + softmax + aggregate -------------------
// 1 block = 1 query, 4 waves. Wave w gathers channels [w*64,w*64+64) ONCE,
// dots its slice against all 8 heads' QK (bf16, wave-uniform s_load + SALU unpack),
// exchanges bf16 partials via LDS, softmax (wave w -> heads 2w,2w+1),
// then lane=channel aggregate from the LDS sample tile.
__global__ __launch_bounds__(256) void k2_attn(
    const ushort* __restrict__ memT, const float* __restrict__ refb,
    const float* __restrict__ OFFb, const ushort* __restrict__ QKb,
    ushort* __restrict__ AGG, float* __restrict__ attnOut) {
    __shared__ unsigned samp[49 * 132];   // bf16 pairs, row stride 132 dwords
    __shared__ unsigned pxb[4][4][64];    // bf16-pair partial scores [wave][h/2][lane]
    __shared__ float attnL[49][8];
    const int t = threadIdx.x;
    const int wid = t >> 6, lane = t & 63;
    const int qu = __builtin_amdgcn_readfirstlane((int)((blockIdx.x & 7) * 512 + (blockIdx.x >> 3)));
    const int b = qu >> 10, n = qu & 1023;
    const bool act = lane < KK;

    const float cx = refb[(size_t)qu * 4 + 0] * 2.f - 1.f;
    const float cy = refb[(size_t)qu * 4 + 1] * 2.f - 1.f;
    float ox = 0.f, oy = 0.f;
    if (act) {
        float2 o2 = *(const float2*)&OFFb[(size_t)qu * 98 + 2 * lane];
        ox = o2.x;
        oy = o2.y;
    }
    float sx = fminf(fmaxf(cx + (float)((lane % 7) - 3) * (2.f / 63.f) + ox, -1.f), 1.f);
    float sy = fminf(fmaxf(cy + (float)(((lane / 7) % 7) - 3) * (2.f / 63.f) + oy, -1.f), 1.f);
    float xf = (sx + 1.f) * 31.5f, yf = (sy + 1.f) * 31.5f;
    float x0f = floorf(xf), y0f = floorf(yf);
    float fx = xf - x0f, fy = yf - y0f;
    int x0 = min(max((int)x0f, 0), 63), y0 = min(max((int)y0f, 0), 63);
    int x1 = min(x0 + 1, 63), y1 = min(y0 + 1, 63);
    float w00 = (1.f - fx) * (1.f - fy), w01 = fx * (1.f - fy);
    float w10 = (1.f - fx) * fy, w11 = fx * fy;

    const ushort* mb = memT + (size_t)b * HWP * DM;
    const ushort* qk0 = QKb + (size_t)__builtin_amdgcn_readfirstlane(qu * 2048 + wid * 64);

    float p[8];
#pragma unroll
    for (int h = 0; h < 8; ++h) p[h] = 0.f;

    // Phase A: gather + lerp + pack to LDS + inline partial dot (this wave's 64 ch)
    if (act) {
        const ushort* p00 = mb + (size_t)(y0 * 64 + x0) * DM + wid * 64;
        const ushort* p01 = mb + (size_t)(y0 * 64 + x1) * DM + wid * 64;
        const ushort* p10 = mb + (size_t)(y1 * 64 + x0) * DM + wid * 64;
        const ushort* p11 = mb + (size_t)(y1 * 64 + x1) * DM + wid * 64;
        unsigned* srow = &samp[lane * 132 + wid * 32];
#pragma unroll 4
        for (int cc = 0; cc < 64; cc += 8) {
            uint4 u00 = *(const uint4*)(p00 + cc);
            uint4 u01 = *(const uint4*)(p01 + cc);
            uint4 u10 = *(const uint4*)(p10 + cc);
            uint4 u11 = *(const uint4*)(p11 + cc);
            const unsigned* a00 = (const unsigned*)&u00;
            const unsigned* a01 = (const unsigned*)&u01;
            const unsigned* a10 = (const unsigned*)&u10;
            const unsigned* a11 = (const unsigned*)&u11;
            float s[8];
#pragma unroll
            for (int q = 0; q < 4; ++q) {
                s[2 * q] = w00 * bflo(a00[q]) + w01 * bflo(a01[q]) +
                           w10 * bflo(a10[q]) + w11 * bflo(a11[q]);
                s[2 * q + 1] = w00 * bfhi(a00[q]) + w01 * bfhi(a01[q]) +
                               w10 * bfhi(a10[q]) + w11 * bfhi(a11[q]);
            }
            uint4 pk;
            pk.x = pack2(s[0], s[1]);
            pk.y = pack2(s[2], s[3]);
            pk.z = pack2(s[4], s[5]);
            pk.w = pack2(s[6], s[7]);
            *(uint4*)&srow[cc / 2] = pk;
#pragma unroll
            for (int h = 0; h < 8; ++h) {
                uint4 qv = *(const uint4*)(qk0 + h * 256 + cc);
                const unsigned* aq = (const unsigned*)&qv;
                p[h] += s[0] * bflo(aq[0]) + s[1] * bfhi(aq[0]) +
                        s[2] * bflo(aq[1]) + s[3] * bfhi(aq[1]) +
                        s[4] * bflo(aq[2]) + s[5] * bfhi(aq[2]) +
                        s[6] * bflo(aq[3]) + s[7] * bfhi(aq[3]);
            }
        }
#pragma unroll
        for (int hp = 0; hp < 4; ++hp)
            pxb[wid][hp][lane] = pack2(p[2 * hp], p[2 * hp + 1]);
    }
    __syncthreads();

    // softmax: wave wid handles heads 2*wid, 2*wid+1 (= head-pair hp = wid)
    float p0 = 0.f, p1 = 0.f;
    if (act) {
#pragma unroll
        for (int w = 0; w < 4; ++w) {
            unsigned u = pxb[w][wid][lane];
            p0 += bflo(u);
            p1 += bfhi(u);
        }
    }
    const float scl = 0.17677669529663687f;  // 1/sqrt(32)
    float s0 = act ? p0 * scl : -INFINITY;
    float s1 = act ? p1 * scl : -INFINITY;
    float m0v = s0, m1v = s1;
#pragma unroll
    for (int off = 32; off; off >>= 1) {
        m0v = fmaxf(m0v, __shfl_xor(m0v, off));
        m1v = fmaxf(m1v, __shfl_xor(m1v, off));
    }
    float e0 = act ? __expf(s0 - m0v) : 0.f;
    float e1 = act ? __expf(s1 - m1v) : 0.f;
    float sum0 = e0, sum1 = e1;
#pragma unroll
    for (int off = 32; off; off >>= 1) {
        sum0 += __shfl_xor(sum0, off);
        sum1 += __shfl_xor(sum1, off);
    }
    float at0 = e0 / sum0, at1 = e1 / sum1;
    if (act) {
        attnL[lane][2 * wid] = at0;
        attnL[lane][2 * wid + 1] = at1;
        attnOut[((size_t)(b * 8 + 2 * wid) * 1024 + n) * 49 + lane] = at0;
        attnOut[((size_t)(b * 8 + 2 * wid + 1) * 1024 + n) * 49 + lane] = at1;
    }
    __syncthreads();

    // Phase B: thread = channel c; acc[h] = sum_k attn[k][h] * samp[k][c]
    const int c = t;
    float acc[8];
#pragma unroll
    for (int h = 0; h < 8; ++h) acc[h] = 0.f;
#pragma unroll 7
    for (int k = 0; k < KK; ++k) {
        unsigned d = samp[k * 132 + (c >> 1)];
        float sv = (c & 1) ? bfhi(d) : bflo(d);
        float4 a0 = *(const float4*)&attnL[k][0];
        float4 a1 = *(const float4*)&attnL[k][4];
        acc[0] += a0.x * sv;
        acc[1] += a0.y * sv;
        acc[2] += a0.z * sv;
        acc[3] += a0.w * sv;
        acc[4] += a1.x * sv;
        acc[5] += a1.y * sv;
        acc[6] += a1.z * sv;
        acc[7] += a1.w * sv;
    }
    ushort* ag = AGG + (size_t)qu * 2048 + c;
#pragma unroll
    for (int h = 0; h < 8; ++h) ag[h * 256] = f2bf(acc[h]);
}

extern "C" void kernel_launch(void* const* d_in, const int* in_sizes, int n_in,
                              void* d_out, int out_size, void* d_ws, size_t ws_size,
                              hipStream_t stream) {
    (void)in_sizes; (void)n_in; (void)out_size; (void)ws_size;
    const float* X     = (const float*)d_in[0];
    const float* refb  = (const float*)d_in[1];
    const float* mem   = (const float*)d_in[2];
    const float* Wq    = (const float*)d_in[3];
    const float* bq    = (const float*)d_in[4];
    const float* Wk    = (const float*)d_in[5];
    const float* Wv    = (const float*)d_in[7];
    const float* bv    = (const float*)d_in[8];
    const float* Wo    = (const float*)d_in[9];
    const float* bo    = (const float*)d_in[10];
    const float* Woff1 = (const float*)d_in[11];
    const float* boff1 = (const float*)d_in[12];
    const float* Woff2 = (const float*)d_in[13];
    const float* boff2 = (const float*)d_in[14];
    const float* sigma = (const float*)d_in[15];

    float* out  = (float*)d_out;
    float* attn = out + (size_t)NQT * DM;  // (B,8,N,49) f32

    float* ws = (float*)d_ws;
    ushort* memT  = (ushort*)(ws + 0);         // 4*4096*256 bf16
    ushort* Xbf   = (ushort*)(ws + 2097152);   // 4096*256 bf16
    ushort* WqkT  = (ushort*)(ws + 2621440);   // 2048*256 bf16
    float*  bqk   = ws + 2883584;              // 2048 f32
    ushort* WvoT  = (ushort*)(ws + 2885632);   // 256*2048 bf16
    float*  bvo   = ws + 3147776;              // 256 f32
    ushort* W1t   = (ushort*)(ws + 3148032);   // 256*256 bf16
    ushort* W2t   = (ushort*)(ws + 3180800);   // 98*256 bf16
    ushort* QKbf  = (ushort*)(ws + 3193344);   // 4096*2048 bf16
    ushort* Hbf   = (ushort*)(ws + 7387648);   // 4096*256 bf16
    float*  OFFb  = ws + 7911936;              // 4096*98 f32
    ushort* AGGb  = (ushort*)(ws + 8313344);   // 4096*2048 bf16  (end ~50 MB)

    // fused prep (cast, transposes, weight folds) — 1 dispatch
    k_prep<<<7008, 256, 0, stream>>>(X, Xbf, mem, memT, Wq, Wk, bq, WqkT, bqk,
                                     Wv, Wo, bv, bo, WvoT, bvo, Woff1, W1t, Woff2, W2t);

    // QK = X @ Wqk + bqk   (M=4096, N=2048, K=256) -> bf16
    gemm_bf16<128, 64, 64, 0, 1><<<dim3(32, 32), 256, 0, stream>>>(
        Xbf, WqkT, bqk, QKbf, 2048, 256, 2048, nullptr);
    // H = relu(X @ Woff1 + boff1) -> bf16   (N=256, K=256)
    gemm_bf16<64, 64, 64, 1, 1><<<dim3(4, 64), 256, 0, stream>>>(
        Xbf, W1t, boff1, Hbf, 256, 256, 256, nullptr);
    // OFF = tanh(H @ Woff2 + boff2) * sigma -> f32  (N=98, K=256)
    gemm_bf16<64, 64, 64, 2, 0><<<dim3(2, 64), 256, 0, stream>>>(
        Hbf, W2t, boff2, OFFb, 98, 256, 98, sigma);

    // fused sampling + scores + softmax + aggregate
    k2_attn<<<4096, 256, 0, stream>>>(memT, refb, OFFb, QKbf, AGGb, attn);

    // out = AGG @ Wvo + bvo  (M=4096, N=256, K=2048) -> f32; 512 blocks (2/CU)
    gemm_bf16<64, 32, 64, 0, 0><<<dim3(8, 64), 256, 0, stream>>>(
        AGGb, WvoT, bvo, out, 256, 2048, 256, nullptr);
}